// Round 8
// baseline (216.863 us; speedup 1.0000x reference)
//
#include <hip/hip_runtime.h>
#include <hip/hip_bf16.h>
#include <math.h>

#define BB 64
#define SS 512
#define DD 1024
#define LL 9
#define NCHUNK 32
#define CLEN 16
#define WSTR 1028  // padded LDS row stride (words): <=2-way conflicts (free)

#define DPP_ADD(v, ctrl)                                                     \
  v += __int_as_float(__builtin_amdgcn_update_dpp(                           \
      0, __float_as_int(v), ctrl, 0xF, 0xF, false))

template <int R>
__device__ inline float swz(float x) {
  return __int_as_float(
      __builtin_amdgcn_ds_swizzle(__float_as_int(x), (R << 10) | 0x1F));
}

// ---------------- GEMM: logits[row][l] = sum_k in[row][k]*W[k][l] + b[l]
// 1024 blocks x 256 threads (4 blocks/CU, 16 waves/CU). Wave = 8 rows:
// p = lane&15 k-splits, sub = lane>>4 picks row (W LDS reads broadcast
// across subs). KEY CHANGE vs r4-r7: 4-deep ROTATING prefetch queue,
// fully unrolled -> consume oldest slot only, re-issue into it; compiler
// emits counted s_waitcnt vmcnt(6) -- the load queue NEVER drains to 0
// inside the loop (T4 principle at register level).
__global__ __launch_bounds__(256, 4) void gemm_kernel(
    const float* __restrict__ in, const float* __restrict__ W,
    const float* __restrict__ bias, float* __restrict__ out) {
  __shared__ float Wt[LL * WSTR];  // 37 KB, [l][k] padded
  int tid = threadIdx.x;
  // src-major: global reads coalesced; LDS writes <=2-way conflicts (free)
  for (int i = tid; i < DD * LL; i += 256) {
    int k = i / LL, l = i - k * LL;  // W row-major [k][l]
    Wt[l * WSTR + k] = W[i];
  }
  __syncthreads();

  int lane = tid & 63;
  int wave = tid >> 6;
  int p = lane & 15;
  int sub = lane >> 4;

  int r0 = blockIdx.x * 32 + wave * 8 + sub;  // rows r0, r0+4
  const float* x0 = in + (size_t)r0 * DD + p * 4;
  const float* x1 = x0 + 4 * DD;

  float acc[2][LL];
#pragma unroll
  for (int q = 0; q < 2; ++q)
#pragma unroll
    for (int l = 0; l < LL; ++l) acc[q][l] = 0.f;

  float4 q0[4], q1[4];  // rotating 4-deep queue (8 loads in flight)
#pragma unroll
  for (int s = 0; s < 4; ++s) {
    q0[s] = *reinterpret_cast<const float4*>(x0 + s * 64);
    q1[s] = *reinterpret_cast<const float4*>(x1 + s * 64);
  }

#pragma unroll
  for (int it = 0; it < 16; ++it) {
    const int s = it & 3;  // static after unroll
    int k0 = it * 64 + p * 4;
#pragma unroll
    for (int l = 0; l < LL; ++l) {
      float4 w4 = *reinterpret_cast<const float4*>(&Wt[l * WSTR + k0]);
      acc[0][l] += q0[s].x * w4.x + q0[s].y * w4.y + q0[s].z * w4.z +
                   q0[s].w * w4.w;
      acc[1][l] += q1[s].x * w4.x + q1[s].y * w4.y + q1[s].z * w4.z +
                   q1[s].w * w4.w;
    }
    if (it < 12) {  // refill slot s with iter it+4's data
      q0[s] = *reinterpret_cast<const float4*>(x0 + (it + 4) * 64);
      q1[s] = *reinterpret_cast<const float4*>(x1 + (it + 4) * 64);
    }
  }

#pragma unroll
  for (int q = 0; q < 2; ++q)
#pragma unroll
    for (int l = 0; l < LL; ++l) {
      DPP_ADD(acc[q][l], 0x111);
      DPP_ADD(acc[q][l], 0x112);
      DPP_ADD(acc[q][l], 0x114);
      DPP_ADD(acc[q][l], 0x118);
    }
  if (p == 15) {
#pragma unroll
    for (int q = 0; q < 2; ++q)
#pragma unroll
      for (int l = 0; l < LL; ++l)
        out[(size_t)(r0 + q * 4) * LL + l] = acc[q][l] + bias[l];
  }
}

// ---------------- Phase 1: per-(batch,chunk) 16-step transfer matrix +
// per-chunk numerator partial. Lane j holds ROW j of T. Mats stored
// pre-permuted: T[i][c] -> offset c*16 + (i^c). Block 0 zeroes the
// finisher counter (combine runs after, stream-ordered).
__global__ __launch_bounds__(64) void crf_chunk_kernel(
    const float* __restrict__ logits, const int* __restrict__ targets,
    const int* __restrict__ seqlen, const float* __restrict__ trans,
    float* __restrict__ mats, float* __restrict__ scales,
    float* __restrict__ numpart, unsigned* __restrict__ counter) {
  if (blockIdx.x == 0 && threadIdx.x == 0) *counter = 0u;

  int lane = threadIdx.x;
  int j = lane & 15;
  int gid = blockIdx.x * 4 + (lane >> 4);
  int b = gid >> 5;
  int k = gid & 31;
  int len = seqlen[b];

  float Mx[81];
#pragma unroll
  for (int i = 0; i < 81; ++i) Mx[i] = __expf(trans[i]);

  float T[LL];
#pragma unroll
  for (int c = 0; c < LL; ++c) T[c] = (j == c) ? 1.f : 0.f;
  float Cl = 0.f;

  const float* lb = logits + (size_t)b * SS * LL;
  const int* tb = targets + (size_t)b * SS;
  int t0 = k * CLEN + 1;
  int tend = (t0 + CLEN < SS) ? (t0 + CLEN) : SS;

  float e[LL];
#pragma unroll
  for (int c = 0; c < LL; ++c) e[c] = lb[t0 * LL + c];

  for (int t = t0; t < tend; ++t) {
    float Ex[LL];
#pragma unroll
    for (int c = 0; c < LL; ++c) Ex[c] = __expf(e[c]);
    if (t + 1 < tend) {
#pragma unroll
      for (int c = 0; c < LL; ++c) e[c] = lb[(t + 1) * LL + c];
    }
    bool active = (t < len);
    float nT[LL];
#pragma unroll
    for (int c = 0; c < LL; ++c) {
      float s = 0.f;
#pragma unroll
      for (int m = 0; m < LL; ++m) s += T[m] * Mx[m * LL + c];
      nT[c] = s * Ex[c];
    }
#pragma unroll
    for (int c = 0; c < LL; ++c) T[c] = active ? nT[c] : T[c];

    if (((t - t0) & 7) == 7) {
      float m = T[0];
#pragma unroll
      for (int c = 1; c < LL; ++c) m = fmaxf(m, T[c]);
      m = fmaxf(m, swz<1>(m));
      m = fmaxf(m, swz<2>(m));
      m = fmaxf(m, swz<4>(m));
      m = fmaxf(m, swz<8>(m));
      float inv = 1.f / m;
#pragma unroll
      for (int c = 0; c < LL; ++c) T[c] *= inv;
      Cl += __logf(m);
    }
  }
  {
    float m = T[0];
#pragma unroll
    for (int c = 1; c < LL; ++c) m = fmaxf(m, T[c]);
    m = fmaxf(m, swz<1>(m));
    m = fmaxf(m, swz<2>(m));
    m = fmaxf(m, swz<4>(m));
    m = fmaxf(m, swz<8>(m));
    float inv = 1.f / m;
#pragma unroll
    for (int c = 0; c < LL; ++c) T[c] *= inv;
    Cl += __logf(m);
  }

  float* Mg = mats + (size_t)gid * 256;
#pragma unroll
  for (int c = 0; c < 16; ++c)
    Mg[c * 16 + (j ^ c)] = (c < LL) ? T[c] : 0.f;
  if (j == 0) scales[gid] = Cl;

  // numerator partial for t in [t0, tend): lane j handles t = t0 + j
  int t = t0 + j;
  float np = 0.f;
  if (t < tend && t < len) {
    int tg = tb[t];
    np = lb[t * LL + tg] + trans[tb[t - 1] * LL + tg];
  }
  np += swz<1>(np);
  np += swz<2>(np);
  np += swz<4>(np);
  np += swz<8>(np);
  if (j == 0) numpart[gid] = np;
}

// ---------------- Phase 2: per-batch combine (matvec tree, renorm every 4
// chunks) + deterministic final reduce via last-block finisher.
__global__ __launch_bounds__(64) void crf_combine_kernel(
    const float* __restrict__ logits, const int* __restrict__ targets,
    const float* __restrict__ mats, const float* __restrict__ scales,
    const float* __restrict__ numpart, float* __restrict__ partials,
    unsigned* __restrict__ counter, float* __restrict__ out_val) {
  int lane = threadIdx.x;
  int j = lane & 15;
  int b = blockIdx.x;
  const float* lb = logits + (size_t)b * SS * LL;
  const float* Mb = mats + (size_t)b * NCHUNK * 256;

  // sum of chunk scales minus numerator partials (fixed order)
  float extra = (lane < NCHUNK) ? scales[b * NCHUNK + lane]
                                : -numpart[b * NCHUNK + (lane - 32)];
  extra += __shfl_xor(extra, 1, 64);
  extra += __shfl_xor(extra, 2, 64);
  extra += __shfl_xor(extra, 4, 64);
  extra += __shfl_xor(extra, 8, 64);
  extra += __shfl_xor(extra, 16, 64);
  extra += __shfl_xor(extra, 32, 64);
  float emit0 = lb[targets[(size_t)b * SS]];  // t=0 numerator term

  float alpha = (j < LL) ? __expf(lb[j]) : 0.f;
  float C = 0.f;

  float4 c0 = *reinterpret_cast<const float4*>(Mb + j * 16 + 0);
  float4 c1 = *reinterpret_cast<const float4*>(Mb + j * 16 + 4);
  float4 c2 = *reinterpret_cast<const float4*>(Mb + j * 16 + 8);
  float4 c3 = *reinterpret_cast<const float4*>(Mb + j * 16 + 12);

  for (int k = 0; k < NCHUNK; ++k) {
    float4 n0, n1, n2, n3;
    if (k + 1 < NCHUNK) {
      const float* Mn = Mb + (size_t)(k + 1) * 256 + j * 16;
      n0 = *reinterpret_cast<const float4*>(Mn + 0);
      n1 = *reinterpret_cast<const float4*>(Mn + 4);
      n2 = *reinterpret_cast<const float4*>(Mn + 8);
      n3 = *reinterpret_cast<const float4*>(Mn + 12);
    }
    float s01 = alpha * c0.x + swz<1>(alpha) * c0.y;
    float s23 = swz<2>(alpha) * c0.z + swz<3>(alpha) * c0.w;
    float s45 = swz<4>(alpha) * c1.x + swz<5>(alpha) * c1.y;
    float s67 = swz<6>(alpha) * c1.z + swz<7>(alpha) * c1.w;
    float s89 = swz<8>(alpha) * c2.x + swz<9>(alpha) * c2.y;
    float sab = swz<10>(alpha) * c2.z + swz<11>(alpha) * c2.w;
    float scd = swz<12>(alpha) * c3.x + swz<13>(alpha) * c3.y;
    float sef = swz<14>(alpha) * c3.z + swz<15>(alpha) * c3.w;
    alpha = ((s01 + s23) + (s45 + s67)) + ((s89 + sab) + (scd + sef));

    if ((k & 3) == 3) {  // renorm every 4 chunks (growth <= 9^4, safe)
      float m = alpha;
      m = fmaxf(m, swz<1>(m));
      m = fmaxf(m, swz<2>(m));
      m = fmaxf(m, swz<4>(m));
      m = fmaxf(m, swz<8>(m));
      float inv = 1.f / m;
      alpha *= inv;
      C += __logf(m);
    }
    if (k + 1 < NCHUNK) { c0 = n0; c1 = n1; c2 = n2; c3 = n3; }
  }

  float s = alpha;
  s += swz<1>(s);
  s += swz<2>(s);
  s += swz<4>(s);
  s += swz<8>(s);
  float result = extra + C + __logf(s) - emit0;

  if (lane == 0) partials[b] = result;
  __threadfence();
  unsigned old = 0;
  if (lane == 0) old = atomicAdd(counter, 1u);
  old = __shfl(old, 0, 64);
  if (old == BB - 1) {  // last block: deterministic fixed-order reduce
    __threadfence();
    float v = partials[lane];
    v += __shfl_xor(v, 1, 64);
    v += __shfl_xor(v, 2, 64);
    v += __shfl_xor(v, 4, 64);
    v += __shfl_xor(v, 8, 64);
    v += __shfl_xor(v, 16, 64);
    v += __shfl_xor(v, 32, 64);
    if (lane == 0) {
      out_val[0] = v;
      *counter = 0u;
    }
  }
}

extern "C" void kernel_launch(void* const* d_in, const int* in_sizes, int n_in,
                              void* d_out, int out_size, void* d_ws,
                              size_t ws_size, hipStream_t stream) {
  const float* inputs = (const float*)d_in[0];
  const int* targets = (const int*)d_in[1];
  const int* seqlen = (const int*)d_in[2];
  const float* W = (const float*)d_in[4];
  const float* bias = (const float*)d_in[5];
  const float* trans = (const float*)d_in[6];
  float* out = (float*)d_out;

  float* mats = (float*)d_ws;                        // 64*32*256 f = 2 MB
  float* scales = mats + (size_t)BB * NCHUNK * 256;  // 2048 f
  float* numpart = scales + (size_t)BB * NCHUNK;     // 2048 f
  float* partials = numpart + (size_t)BB * NCHUNK;   // 64 f
  unsigned* counter = (unsigned*)(partials + BB);    // 1 u32

  gemm_kernel<<<1024, 256, 0, stream>>>(inputs, W, bias, out + 1);
  crf_chunk_kernel<<<BB * NCHUNK / 4, 64, 0, stream>>>(
      out + 1, targets, seqlen, trans, mats, scales, numpart, counter);
  crf_combine_kernel<<<BB, 64, 0, stream>>>(out + 1, targets, mats, scales,
                                            numpart, partials, counter, out);
}

// Round 9
// 59.039 us; speedup vs baseline: 3.6732x; 3.6732x over previous
//
#include <hip/hip_runtime.h>
#include <hip/hip_bf16.h>
#include <math.h>

#define BB 64
#define SS 512
#define DD 1024
#define LL 9
#define NCHUNK 32
#define CLEN 16

#define DPP_ADD(v, ctrl)                                                     \
  v += __int_as_float(__builtin_amdgcn_update_dpp(                           \
      0, __float_as_int(v), ctrl, 0xF, 0xF, false))
// full-wave sum -> lane 63: row_shr 1,2,4,8 + row_bcast15 + row_bcast31
// (verified on-device in r5/r6 kernels)
#define WAVE_RED63(v)                                                        \
  do {                                                                       \
    DPP_ADD(v, 0x111);                                                       \
    DPP_ADD(v, 0x112);                                                       \
    DPP_ADD(v, 0x114);                                                       \
    DPP_ADD(v, 0x118);                                                       \
    DPP_ADD(v, 0x142);                                                       \
    DPP_ADD(v, 0x143);                                                       \
  } while (0)

// static-index float4 component access (folds at compile time)
#define GETC(v, c)                                                           \
  ((c) == 0 ? (v).x : (c) == 1 ? (v).y : (c) == 2 ? (v).z : (v).w)

template <int R>
__device__ inline float swz(float x) {
  return __int_as_float(
      __builtin_amdgcn_ds_swizzle(__float_as_int(x), (R << 10) | 0x1F));
}

// ---------------- GEMM: logits[row][l] = sum_k in[row][k]*W[k][l] + b[l]
// ZERO-LDS variant. 512 blocks x 256 thr (2 blocks/CU, 8 waves/CU at
// ~206 VGPR). Wave covers ONE FULL ROW: lane owns k in [lane*16,lane*16+16)
// -- row-invariant, so lane's W fragment (16k x 9l = 144 floats) is
// CONTIGUOUS (W + lane*576B) and loaded into 36 float4 REGISTERS once.
// Hot loop: 4 contiguous float4 global loads/row (wave streams each 4KB
// row exactly; 64KB sequential per wave), 144 reg FMAs, 9 DPP wave
// reduces, lane-63 stores. No LDS, no per-iter W traffic.
__global__ __launch_bounds__(256, 2) void gemm_kernel(
    const float* __restrict__ in, const float* __restrict__ W,
    const float* __restrict__ bias, float* __restrict__ out) {
  int tid = threadIdx.x;
  int lane = tid & 63;
  int wave = tid >> 6;

  // W fragment: 36 contiguous float4s per lane (lane*576 B, 16B-aligned)
  float4 wf[36];
  {
    const float* wsrc = W + (size_t)lane * (16 * LL);
#pragma unroll
    for (int j = 0; j < 36; ++j)
      wf[j] = *reinterpret_cast<const float4*>(wsrc + j * 4);
  }
  float bv[LL];
#pragma unroll
  for (int l = 0; l < LL; ++l) bv[l] = bias[l];

  int rbase = blockIdx.x * 64 + wave * 16;  // 16 consecutive rows per wave
  const float* src = in + (size_t)rbase * DD + lane * 16;

  float4 a[4], an[4];
#pragma unroll
  for (int c = 0; c < 4; ++c)
    a[c] = *reinterpret_cast<const float4*>(src + c * 4);

  for (int ri = 0; ri < 16; ++ri) {
    if (ri < 15) {
      const float* nsrc = src + (size_t)(ri + 1) * DD;
#pragma unroll
      for (int c = 0; c < 4; ++c)
        an[c] = *reinterpret_cast<const float4*>(nsrc + c * 4);
    }

    float acc[LL];
#pragma unroll
    for (int l = 0; l < LL; ++l) acc[l] = 0.f;
#pragma unroll
    for (int i = 0; i < 16; ++i) {
      float av = GETC(a[i >> 2], i & 3);
#pragma unroll
      for (int l = 0; l < LL; ++l) {
        const int idx = i * LL + l;
        acc[l] += av * GETC(wf[idx >> 2], idx & 3);
      }
    }

#pragma unroll
    for (int l = 0; l < LL; ++l) WAVE_RED63(acc[l]);
    if (lane == 63) {
      float* g = out + (size_t)(rbase + ri) * LL;
#pragma unroll
      for (int l = 0; l < LL; ++l) g[l] = acc[l] + bv[l];
    }

    if (ri < 15) {
#pragma unroll
      for (int c = 0; c < 4; ++c) a[c] = an[c];
    }
  }
}

// ---------------- Phase 1: per-(batch,chunk) 16-step transfer matrix +
// per-chunk numerator partial. Lane j holds ROW j of T. Mats stored
// pre-permuted: T[i][c] -> offset c*16 + (i^c). Block 0 zeroes the
// finisher counter (combine runs after, stream-ordered).
__global__ __launch_bounds__(64) void crf_chunk_kernel(
    const float* __restrict__ logits, const int* __restrict__ targets,
    const int* __restrict__ seqlen, const float* __restrict__ trans,
    float* __restrict__ mats, float* __restrict__ scales,
    float* __restrict__ numpart, unsigned* __restrict__ counter) {
  if (blockIdx.x == 0 && threadIdx.x == 0) *counter = 0u;

  int lane = threadIdx.x;
  int j = lane & 15;
  int gid = blockIdx.x * 4 + (lane >> 4);
  int b = gid >> 5;
  int k = gid & 31;
  int len = seqlen[b];

  float Mx[81];
#pragma unroll
  for (int i = 0; i < 81; ++i) Mx[i] = __expf(trans[i]);

  float T[LL];
#pragma unroll
  for (int c = 0; c < LL; ++c) T[c] = (j == c) ? 1.f : 0.f;
  float Cl = 0.f;

  const float* lb = logits + (size_t)b * SS * LL;
  const int* tb = targets + (size_t)b * SS;
  int t0 = k * CLEN + 1;
  int tend = (t0 + CLEN < SS) ? (t0 + CLEN) : SS;

  float e[LL];
#pragma unroll
  for (int c = 0; c < LL; ++c) e[c] = lb[t0 * LL + c];

  for (int t = t0; t < tend; ++t) {
    float Ex[LL];
#pragma unroll
    for (int c = 0; c < LL; ++c) Ex[c] = __expf(e[c]);
    if (t + 1 < tend) {
#pragma unroll
      for (int c = 0; c < LL; ++c) e[c] = lb[(t + 1) * LL + c];
    }
    bool active = (t < len);
    float nT[LL];
#pragma unroll
    for (int c = 0; c < LL; ++c) {
      float s = 0.f;
#pragma unroll
      for (int m = 0; m < LL; ++m) s += T[m] * Mx[m * LL + c];
      nT[c] = s * Ex[c];
    }
#pragma unroll
    for (int c = 0; c < LL; ++c) T[c] = active ? nT[c] : T[c];

    if (((t - t0) & 7) == 7) {
      float m = T[0];
#pragma unroll
      for (int c = 1; c < LL; ++c) m = fmaxf(m, T[c]);
      m = fmaxf(m, swz<1>(m));
      m = fmaxf(m, swz<2>(m));
      m = fmaxf(m, swz<4>(m));
      m = fmaxf(m, swz<8>(m));
      float inv = 1.f / m;
#pragma unroll
      for (int c = 0; c < LL; ++c) T[c] *= inv;
      Cl += __logf(m);
    }
  }
  {
    float m = T[0];
#pragma unroll
    for (int c = 1; c < LL; ++c) m = fmaxf(m, T[c]);
    m = fmaxf(m, swz<1>(m));
    m = fmaxf(m, swz<2>(m));
    m = fmaxf(m, swz<4>(m));
    m = fmaxf(m, swz<8>(m));
    float inv = 1.f / m;
#pragma unroll
    for (int c = 0; c < LL; ++c) T[c] *= inv;
    Cl += __logf(m);
  }

  float* Mg = mats + (size_t)gid * 256;
#pragma unroll
  for (int c = 0; c < 16; ++c)
    Mg[c * 16 + (j ^ c)] = (c < LL) ? T[c] : 0.f;
  if (j == 0) scales[gid] = Cl;

  // numerator partial for t in [t0, tend): lane j handles t = t0 + j
  int t = t0 + j;
  float np = 0.f;
  if (t < tend && t < len) {
    int tg = tb[t];
    np = lb[t * LL + tg] + trans[tb[t - 1] * LL + tg];
  }
  np += swz<1>(np);
  np += swz<2>(np);
  np += swz<4>(np);
  np += swz<8>(np);
  if (j == 0) numpart[gid] = np;
}

// ---------------- Phase 2: per-batch combine (matvec tree, renorm every 4
// chunks) + deterministic final reduce via last-block finisher.
__global__ __launch_bounds__(64) void crf_combine_kernel(
    const float* __restrict__ logits, const int* __restrict__ targets,
    const float* __restrict__ mats, const float* __restrict__ scales,
    const float* __restrict__ numpart, float* __restrict__ partials,
    unsigned* __restrict__ counter, float* __restrict__ out_val) {
  int lane = threadIdx.x;
  int j = lane & 15;
  int b = blockIdx.x;
  const float* lb = logits + (size_t)b * SS * LL;
  const float* Mb = mats + (size_t)b * NCHUNK * 256;

  // sum of chunk scales minus numerator partials (fixed order)
  float extra = (lane < NCHUNK) ? scales[b * NCHUNK + lane]
                                : -numpart[b * NCHUNK + (lane - 32)];
  extra += __shfl_xor(extra, 1, 64);
  extra += __shfl_xor(extra, 2, 64);
  extra += __shfl_xor(extra, 4, 64);
  extra += __shfl_xor(extra, 8, 64);
  extra += __shfl_xor(extra, 16, 64);
  extra += __shfl_xor(extra, 32, 64);
  float emit0 = lb[targets[(size_t)b * SS]];  // t=0 numerator term

  float alpha = (j < LL) ? __expf(lb[j]) : 0.f;
  float C = 0.f;

  float4 c0 = *reinterpret_cast<const float4*>(Mb + j * 16 + 0);
  float4 c1 = *reinterpret_cast<const float4*>(Mb + j * 16 + 4);
  float4 c2 = *reinterpret_cast<const float4*>(Mb + j * 16 + 8);
  float4 c3 = *reinterpret_cast<const float4*>(Mb + j * 16 + 12);

  for (int k = 0; k < NCHUNK; ++k) {
    float4 n0, n1, n2, n3;
    if (k + 1 < NCHUNK) {
      const float* Mn = Mb + (size_t)(k + 1) * 256 + j * 16;
      n0 = *reinterpret_cast<const float4*>(Mn + 0);
      n1 = *reinterpret_cast<const float4*>(Mn + 4);
      n2 = *reinterpret_cast<const float4*>(Mn + 8);
      n3 = *reinterpret_cast<const float4*>(Mn + 12);
    }
    float s01 = alpha * c0.x + swz<1>(alpha) * c0.y;
    float s23 = swz<2>(alpha) * c0.z + swz<3>(alpha) * c0.w;
    float s45 = swz<4>(alpha) * c1.x + swz<5>(alpha) * c1.y;
    float s67 = swz<6>(alpha) * c1.z + swz<7>(alpha) * c1.w;
    float s89 = swz<8>(alpha) * c2.x + swz<9>(alpha) * c2.y;
    float sab = swz<10>(alpha) * c2.z + swz<11>(alpha) * c2.w;
    float scd = swz<12>(alpha) * c3.x + swz<13>(alpha) * c3.y;
    float sef = swz<14>(alpha) * c3.z + swz<15>(alpha) * c3.w;
    alpha = ((s01 + s23) + (s45 + s67)) + ((s89 + sab) + (scd + sef));

    if ((k & 3) == 3) {  // renorm every 4 chunks (growth <= 9^4, safe)
      float m = alpha;
      m = fmaxf(m, swz<1>(m));
      m = fmaxf(m, swz<2>(m));
      m = fmaxf(m, swz<4>(m));
      m = fmaxf(m, swz<8>(m));
      float inv = 1.f / m;
      alpha *= inv;
      C += __logf(m);
    }
    if (k + 1 < NCHUNK) { c0 = n0; c1 = n1; c2 = n2; c3 = n3; }
  }

  float s = alpha;
  s += swz<1>(s);
  s += swz<2>(s);
  s += swz<4>(s);
  s += swz<8>(s);
  float result = extra + C + __logf(s) - emit0;

  if (lane == 0) partials[b] = result;
  __threadfence();
  unsigned old = 0;
  if (lane == 0) old = atomicAdd(counter, 1u);
  old = __shfl(old, 0, 64);
  if (old == BB - 1) {  // last block: deterministic fixed-order reduce
    __threadfence();
    float v = partials[lane];
    v += __shfl_xor(v, 1, 64);
    v += __shfl_xor(v, 2, 64);
    v += __shfl_xor(v, 4, 64);
    v += __shfl_xor(v, 8, 64);
    v += __shfl_xor(v, 16, 64);
    v += __shfl_xor(v, 32, 64);
    if (lane == 0) {
      out_val[0] = v;
      *counter = 0u;
    }
  }
}

extern "C" void kernel_launch(void* const* d_in, const int* in_sizes, int n_in,
                              void* d_out, int out_size, void* d_ws,
                              size_t ws_size, hipStream_t stream) {
  const float* inputs = (const float*)d_in[0];
  const int* targets = (const int*)d_in[1];
  const int* seqlen = (const int*)d_in[2];
  const float* W = (const float*)d_in[4];
  const float* bias = (const float*)d_in[5];
  const float* trans = (const float*)d_in[6];
  float* out = (float*)d_out;

  float* mats = (float*)d_ws;                        // 64*32*256 f = 2 MB
  float* scales = mats + (size_t)BB * NCHUNK * 256;  // 2048 f
  float* numpart = scales + (size_t)BB * NCHUNK;     // 2048 f
  float* partials = numpart + (size_t)BB * NCHUNK;   // 64 f
  unsigned* counter = (unsigned*)(partials + BB);    // 1 u32

  gemm_kernel<<<512, 256, 0, stream>>>(inputs, W, bias, out + 1);
  crf_chunk_kernel<<<BB * NCHUNK / 4, 64, 0, stream>>>(
      out + 1, targets, seqlen, trans, mats, scales, numpart, counter);
  crf_combine_kernel<<<BB, 64, 0, stream>>>(out + 1, targets, mats, scales,
                                            numpart, partials, counter, out);
}